// Round 2
// baseline (859.085 us; speedup 1.0000x reference)
//
#include <hip/hip_runtime.h>

typedef float f32x4 __attribute__((ext_vector_type(4)));

constexpr int   N     = 512;
constexpr int   NITER = 21;
// (1/temperature) * log2(e): work entirely in base-2 so v_exp_f32 / v_log_f32
// are used natively with no ln2/log2e fixup multiplies.
constexpr float C2 = 144.26950408889634f;

#define EXP2(x) __builtin_amdgcn_exp2f(x)
#define LOG2(x) __builtin_amdgcn_logf(x)
#define RCP(x)  __builtin_amdgcn_rcpf(x)

// 1 block per matrix, 1024 threads = 16 waves (1 block/CU -> 16 waves/CU,
// so a 128-VGPR budget costs nothing: __launch_bounds__(1024, 4)).
// wave w owns rows [32w, 32w+32); lane l owns cols {4l..4l+3, 256+4l..259+4l}.
__launch_bounds__(1024, 4)
__global__ void sinkhorn_kernel(const float* __restrict__ x,
                                float* __restrict__ out) {
    __shared__ alignas(16) float cpart[16][N];  // 32 KiB column partials
    __shared__ float u_s[N];                    // row potentials (base-2)
    __shared__ alignas(16) float v_s[N];        // col potentials (base-2)

    const int tid  = threadIdx.x;
    const int wave = tid >> 6;
    const int lane = tid & 63;
    const int j0   = lane << 2;

    const size_t base = (size_t)blockIdx.x * (size_t)(N * N);
    const float* __restrict__ xb = x + base;
    const int row0 = wave * 32;

    for (int j = tid; j < N; j += 1024) { u_s[j] = 0.0f; v_s[j] = 0.0f; }
    __syncthreads();

    for (int it = 0; it < NITER; ++it) {
        const f32x4 va = *(const f32x4*)&v_s[j0];
        const f32x4 vb = *(const f32x4*)&v_s[256 + j0];
        const float vl[8] = {va.x, va.y, va.z, va.w, vb.x, vb.y, vb.z, vb.w};
        float cac[8] = {0.f, 0.f, 0.f, 0.f, 0.f, 0.f, 0.f, 0.f};

        #pragma unroll 1
        for (int g = 0; g < 4; ++g) {
            const int rbase = row0 + g * 8;
            // issue all 16 loads for this 8-row group up front
            f32x4 xa[8], xc[8];
            #pragma unroll
            for (int r = 0; r < 8; ++r) {
                const float* row = xb + (size_t)(rbase + r) * N;
                xa[r] = *(const f32x4*)(row + j0);
                xc[r] = *(const f32x4*)(row + 256 + j0);
            }

            float ush[8];
            if (it == 0) {
                // shift = row max of y2 (v == 0): exact first LSE
                #pragma unroll
                for (int r = 0; r < 8; ++r) {
                    float m0 = fmaxf(fmaxf(xa[r].x, xa[r].y), fmaxf(xa[r].z, xa[r].w));
                    float m1 = fmaxf(fmaxf(xc[r].x, xc[r].y), fmaxf(xc[r].z, xc[r].w));
                    ush[r] = fmaxf(m0, m1) * C2;   // C2 > 0: max commutes with scale
                }
                #pragma unroll
                for (int off = 32; off > 0; off >>= 1) {
                    #pragma unroll
                    for (int r = 0; r < 8; ++r)
                        ush[r] = fmaxf(ush[r], __shfl_xor(ush[r], off, 64));
                }
            } else {
                // shift = u^{it-1}: y2 - v - u = log2_alpha^{it-1} <= 0, exp-safe
                #pragma unroll
                for (int r = 0; r < 8; ++r) ush[r] = u_s[rbase + r];
            }

            float e[8][8], s[8];
            #pragma unroll
            for (int r = 0; r < 8; ++r) {
                const float xv[8] = {xa[r].x, xa[r].y, xa[r].z, xa[r].w,
                                     xc[r].x, xc[r].y, xc[r].z, xc[r].w};
                float s0 = 0.f, s1 = 0.f;
                #pragma unroll
                for (int k = 0; k < 8; ++k) {
                    const float w = vl[k] + ush[r];
                    e[r][k] = EXP2(fmaf(xv[k], C2, -w));
                    if (k & 1) s1 += e[r][k]; else s0 += e[r][k];
                }
                s[r] = s0 + s1;
            }
            // 8 interleaved butterfly reductions (independent chains -> ILP)
            #pragma unroll
            for (int off = 32; off > 0; off >>= 1) {
                #pragma unroll
                for (int r = 0; r < 8; ++r)
                    s[r] += __shfl_xor(s[r], off, 64);
            }
            #pragma unroll
            for (int r = 0; r < 8; ++r) {
                const float sc = fmaxf(s[r], 1e-37f);
                const float a  = RCP(sc);   // exp2(ush - u_new)
                #pragma unroll
                for (int k = 0; k < 8; ++k)
                    cac[k] = fmaf(e[r][k], a, cac[k]);
                if (lane == 0) u_s[rbase + r] = ush[r] + LOG2(sc);  // u^{it}
            }
        }

        // cross-wave column reduction -> v^{it}
        *(f32x4*)&cpart[wave][j0]       = (f32x4){cac[0], cac[1], cac[2], cac[3]};
        *(f32x4*)&cpart[wave][256 + j0] = (f32x4){cac[4], cac[5], cac[6], cac[7]};
        __syncthreads();
        if (tid < N) {
            float s = 0.f;
            #pragma unroll
            for (int w = 0; w < 16; ++w) s += cpart[w][tid];
            v_s[tid] += LOG2(fmaxf(s, 1e-37f));
        }
        __syncthreads();
    }

    // final: out = exp2(y2 - u - v), nontemporal stores
    {
        const f32x4 va = *(const f32x4*)&v_s[j0];
        const f32x4 vb = *(const f32x4*)&v_s[256 + j0];
        const float vl[8] = {va.x, va.y, va.z, va.w, vb.x, vb.y, vb.z, vb.w};
        float* __restrict__ ob = out + base;
        #pragma unroll 1
        for (int g = 0; g < 4; ++g) {
            const int rbase = row0 + g * 8;
            f32x4 xa[8], xc[8];
            #pragma unroll
            for (int r = 0; r < 8; ++r) {
                const float* row = xb + (size_t)(rbase + r) * N;
                xa[r] = *(const f32x4*)(row + j0);
                xc[r] = *(const f32x4*)(row + 256 + j0);
            }
            #pragma unroll
            for (int r = 0; r < 8; ++r) {
                const float ush = u_s[rbase + r];
                const float xv[8] = {xa[r].x, xa[r].y, xa[r].z, xa[r].w,
                                     xc[r].x, xc[r].y, xc[r].z, xc[r].w};
                f32x4 o0, o1;
                float ov[8];
                #pragma unroll
                for (int k = 0; k < 8; ++k) {
                    const float w = vl[k] + ush;
                    ov[k] = EXP2(fmaf(xv[k], C2, -w));
                }
                o0 = (f32x4){ov[0], ov[1], ov[2], ov[3]};
                o1 = (f32x4){ov[4], ov[5], ov[6], ov[7]};
                float* orow = ob + (size_t)(rbase + r) * N;
                __builtin_nontemporal_store(o0, (f32x4*)(orow + j0));
                __builtin_nontemporal_store(o1, (f32x4*)(orow + 256 + j0));
            }
        }
    }
}

extern "C" void kernel_launch(void* const* d_in, const int* in_sizes, int n_in,
                              void* d_out, int out_size, void* d_ws, size_t ws_size,
                              hipStream_t stream) {
    const float* x = (const float*)d_in[0];
    float* out = (float*)d_out;
    const int nmat = in_sizes[0] / (N * N);   // 256
    sinkhorn_kernel<<<nmat, 1024, 0, stream>>>(x, out);
}